// Round 7
// baseline (287.593 us; speedup 1.0000x reference)
//
#include <hip/hip_runtime.h>
#include <stdint.h>

// Fused HashGrid encoder + 32->128(relu)->64 MLP, bf16 MFMA (16x16x32).
//
// Stage 0 (tconv_prep_kernel): tables fp32x2 -> packed bf16x2 (64->32 MB in
// d_ws; bit-identical to casting gathered features later) + W1^T/W2^T MFMA
// fragment packing (k-map kappa(g,j)=16*(j>>2)+4g+(j&3), shared by both
// GEMMs so layer-1's C fragment feeds layer-2's B fragment in-register).
//
// Stage 1 (fused_kernel): R7 — gather and MLP fused; the 64 MB xw write +
// 64 MB read round trip and 16x coord re-reads of the two-pass design are
// eliminated. Per wave (64 pts): compute all 16 level indices, issue 16
// concurrent gathers/lane from the bf16 tables (32 MB, L3-resident; ~2-3
// tables live per XCD L2 since all resident blocks walk levels in the same
// order), deposit words into LDS xbuf[pt][lv] (stride 20 words: ds_read_b128
// of 4 consecutive levels is perfectly bank-balanced), then per 16-pt tile:
// MFMA layer1+layer2 and the obuf LDS transpose so each out store covers a
// contiguous 1 KB (plain stores; nontemporal regressed in R3). Wave-local
// data only -> no __syncthreads anywhere.

typedef __attribute__((ext_vector_type(8))) __bf16 bf16x8;
typedef __attribute__((ext_vector_type(4))) float  f32x4;
typedef __attribute__((ext_vector_type(2))) float  f32x2;

#define NPTS   1048576
#define NTILES 65536

__device__ __forceinline__ unsigned pack_bf16(float x, float y) {
  __bf16 a = (__bf16)x, b = (__bf16)y;
  unsigned short ua, ub;
  __builtin_memcpy(&ua, &a, 2);
  __builtin_memcpy(&ub, &b, 2);
  return (unsigned)ua | ((unsigned)ub << 16);
}

// ---------------- Stage 0: table bf16 conversion + weight prep ----------
__global__ __launch_bounds__(256) void tconv_prep_kernel(
    const float* __restrict__ tables,
    const float* __restrict__ W1, const float* __restrict__ W2,
    unsigned* __restrict__ tb2, short* __restrict__ w1p, short* __restrict__ w2p)
{
  if (blockIdx.x < 8192) {
    int e0 = (blockIdx.x * 256 + threadIdx.x) * 4;
#pragma unroll
    for (int i = 0; i < 4; ++i) {
      int e = e0 + i;
      f32x2 f = *(const f32x2*)(tables + (size_t)e * 2);
      tb2[e] = pack_bf16(f.x, f.y);
    }
    return;
  }
  int tid = (blockIdx.x - 8192) * 256 + threadIdx.x;   // 0..1535
  int l = tid & 63;
  int g = l >> 4;
  int c = l & 15;
  if (tid < 512) {
    int t = tid >> 6;
    bf16x8 v;
#pragma unroll
    for (int j = 0; j < 8; ++j)
      v[j] = (__bf16)W1[(8*g + j)*128 + 16*t + c];
    *(bf16x8*)(w1p + (size_t)(t*64 + l)*8) = v;
  } else if (tid < 1536) {
    int e = (tid - 512) >> 6;
    int mt = e >> 2, ks = e & 3;
    bf16x8 v;
#pragma unroll
    for (int j = 0; j < 8; ++j)
      v[j] = (__bf16)W2[(32*ks + 16*(j>>2) + 4*g + (j&3))*64 + 16*mt + c];
    *(bf16x8*)(w2p + (size_t)(e*64 + l)*8) = v;
  }
}

// ---------------- Stage 1: fused gather + MFMA MLP ----------------
// 4096 blocks x 4 waves; block owns 256 consecutive points (16 tiles),
// wave w owns points w*64..w*64+63 (tiles b*16 + w*4 + t).
__global__ __launch_bounds__(256) void fused_kernel(
    const float* __restrict__ coords, const unsigned* __restrict__ tb2,
    const float* __restrict__ b1, const float* __restrict__ b2,
    const short* __restrict__ w1p, const short* __restrict__ w2p,
    float* __restrict__ out)
{
  const int l = threadIdx.x & 63;
  const int g = l >> 4;
  const int c = l & 15;
  const int w = threadIdx.x >> 6;

  __shared__ unsigned xbuf[256][20];   // [block-local pt][level], stride 20
  __shared__ float obuf[4][16][68];    // per-wave output transpose buffer

  // int(16 * (2048/16)**(l/15)); compile-time constants in the unrolled loops
  constexpr unsigned Rt[16] = {16u,22u,30u,42u,58u,80u,111u,153u,
                               212u,294u,406u,561u,776u,1072u,1482u,2048u};

  bf16x8 w1f[8];
#pragma unroll
  for (int t = 0; t < 8; ++t)
    w1f[t] = *(const bf16x8*)(w1p + (size_t)(t*64 + l)*8);

  // ---- gather phase: this lane's point, all 16 levels ----
  const int ptl = w*64 + l;                       // block-local point
  const int p   = blockIdx.x*256 + ptl;           // global point
  const float u0 = (coords[3*p+0] + 1.0f) * 0.5f;
  const float u1 = (coords[3*p+1] + 1.0f) * 0.5f;
  const float u2 = (coords[3*p+2] + 1.0f) * 0.5f;

  unsigned idx[16];
#pragma unroll
  for (int lv = 0; lv < 16; ++lv) {
    const unsigned R = Rt[lv];
    const float fR = (float)R;
    const unsigned Rm1 = R - 1u;
    const unsigned M = (lv >= 6) ? 0x7FFFFu : 0xFFFFFFFFu;
    unsigned d0 = (unsigned)(int)(u0 * fR); if (d0 > Rm1) d0 = Rm1;
    unsigned d1 = (unsigned)(int)(u1 * fR); if (d1 > Rm1) d1 = Rm1;
    unsigned d2 = (unsigned)(int)(u2 * fR); if (d2 > Rm1) d2 = Rm1;
    // uint32 wraparound matches reference (T=2^19 divides 2^32 when masked)
    idx[lv] = (d0*(R*R) + d1*R + d2) & M;
  }
  unsigned val[16];
#pragma unroll
  for (int lv = 0; lv < 16; ++lv)               // 16 loads in flight
    val[lv] = tb2[((size_t)lv << 19) + idx[lv]];
#pragma unroll
  for (int lv = 0; lv < 16; ++lv)
    xbuf[ptl][lv] = val[lv];
  asm volatile("s_waitcnt lgkmcnt(0)" ::: "memory");  // wave-local: no barrier
  __builtin_amdgcn_sched_barrier(0);

  // ---- MFMA phase: 4 tiles of 16 points ----
#pragma unroll
  for (int t = 0; t < 4; ++t) {
    union { bf16x8 v; f32x4 f; } X;
    X.f = *(const f32x4*)&xbuf[w*64 + t*16 + c][4*g];  // levels 4g..4g+3
    bf16x8 xf = X.v;

    f32x4 h[8];
#pragma unroll
    for (int tt = 0; tt < 8; ++tt) {
      h[tt] = *(const f32x4*)(b1 + 16*tt + 4*g);
      h[tt] = __builtin_amdgcn_mfma_f32_16x16x32_bf16(w1f[tt], xf, h[tt], 0, 0, 0);
    }

    f32x4 o[4];
#pragma unroll
    for (int mt = 0; mt < 4; ++mt)
      o[mt] = *(const f32x4*)(b2 + 16*mt + 4*g);
#pragma unroll
    for (int ks = 0; ks < 4; ++ks) {
      bf16x8 bp;
#pragma unroll
      for (int j = 0; j < 8; ++j) {
        float v = h[2*ks + (j>>2)][j & 3];
        v = fmaxf(v, 0.0f);               // fused ReLU
        bp[j] = (__bf16)v;
      }
#pragma unroll
      for (int mt = 0; mt < 4; ++mt) {
        bf16x8 w2f = *(const bf16x8*)(w2p + (size_t)((mt*4 + ks)*64 + l)*8);
        o[mt] = __builtin_amdgcn_mfma_f32_16x16x32_bf16(w2f, bp, o[mt], 0, 0, 0);
      }
    }

    // obuf LDS transpose -> each store instruction covers contiguous 1 KB.
    float (*ob)[68] = obuf[w];
#pragma unroll
    for (int mt = 0; mt < 4; ++mt)
      *(f32x4*)&ob[c][16*mt + 4*g] = o[mt];
    asm volatile("s_waitcnt lgkmcnt(0)" ::: "memory");
    f32x4 v[4];
#pragma unroll
    for (int s = 0; s < 4; ++s)
      v[s] = *(const f32x4*)&ob[4*s + g][4*c];
    asm volatile("" ::: "memory");
    float* op = out + (size_t)(blockIdx.x*16 + w*4 + t) * 1024;
#pragma unroll
    for (int s = 0; s < 4; ++s)
      *(f32x4*)(op + (4*s + g)*64 + 4*c) = v[s];
    if (t < 3) asm volatile("s_waitcnt lgkmcnt(0)" ::: "memory");
  }
}

// ---------------- R1 fused-from-fp32 kernel kept as ws-too-small fallback --
__global__ void prep_kernel(const float* __restrict__ W1, const float* __restrict__ W2,
                            short* __restrict__ w1p, short* __restrict__ w2p) {
  int tid = blockIdx.x * blockDim.x + threadIdx.x;
  int l = tid & 63;
  int g = l >> 4;
  int c = l & 15;
  if (tid < 512) {
    int t = tid >> 6;
    bf16x8 v;
#pragma unroll
    for (int j = 0; j < 8; ++j)
      v[j] = (__bf16)W1[(8*g + j)*128 + 16*t + c];
    *(bf16x8*)(w1p + (size_t)(t*64 + l)*8) = v;
  } else if (tid < 1536) {
    int e = (tid - 512) >> 6;
    int mt = e >> 2, ks = e & 3;
    bf16x8 v;
#pragma unroll
    for (int j = 0; j < 8; ++j)
      v[j] = (__bf16)W2[(32*ks + 16*(j>>2) + 4*g + (j&3))*64 + 16*mt + c];
    *(bf16x8*)(w2p + (size_t)(e*64 + l)*8) = v;
  }
}

__device__ const unsigned kRES[16] = {16u,22u,30u,42u,58u,80u,111u,153u,
                                      212u,294u,406u,561u,776u,1072u,1482u,2048u};

__global__ __launch_bounds__(256, 3) void hashgrid_mlp_kernel(
    const float* __restrict__ coords, const float* __restrict__ tables,
    const float* __restrict__ b1, const float* __restrict__ b2,
    const short* __restrict__ w1p, const short* __restrict__ w2p,
    float* __restrict__ out, int stride)
{
  const int l = threadIdx.x & 63;
  const int g = l >> 4;
  const int c = l & 15;

  unsigned Rq[4], RRq[4], Mq[4]; float fRq[4];
#pragma unroll
  for (int q = 0; q < 4; ++q) {
    int lv = 4*g + q;
    unsigned R = kRES[lv];
    Rq[q] = R; RRq[q] = R*R; fRq[q] = (float)R;
    Mq[q] = (lv >= 6) ? 0x7FFFFu : 0xFFFFFFFFu;
  }
  const float* tb = tables + ((size_t)g << 22);

  bf16x8 w1f[8];
#pragma unroll
  for (int t = 0; t < 8; ++t)
    w1f[t] = *(const bf16x8*)(w1p + (size_t)(t*64 + l)*8);

  f32x2 gx[4];
  auto prefetch = [&](int tile) {
    int p = tile*16 + c;
    float u0 = (coords[3*p+0] + 1.0f) * 0.5f;
    float u1 = (coords[3*p+1] + 1.0f) * 0.5f;
    float u2 = (coords[3*p+2] + 1.0f) * 0.5f;
#pragma unroll
    for (int q = 0; q < 4; ++q) {
      unsigned Rm1 = Rq[q] - 1u;
      unsigned d0 = (unsigned)(int)(u0 * fRq[q]); if (d0 > Rm1) d0 = Rm1;
      unsigned d1 = (unsigned)(int)(u1 * fRq[q]); if (d1 > Rm1) d1 = Rm1;
      unsigned d2 = (unsigned)(int)(u2 * fRq[q]); if (d2 > Rm1) d2 = Rm1;
      unsigned idx = (d0*RRq[q] + d1*Rq[q] + d2) & Mq[q];
      gx[q] = *(const f32x2*)(tb + ((size_t)q << 20) + (size_t)idx*2u);
    }
  };

  int tile = blockIdx.x * 4 + (threadIdx.x >> 6);
  prefetch(tile);
  while (true) {
    bf16x8 xf;
#pragma unroll
    for (int q = 0; q < 4; ++q) {
      xf[2*q]   = (__bf16)gx[q].x;
      xf[2*q+1] = (__bf16)gx[q].y;
    }
    int cur = tile;
    tile += stride;
    if (tile < NTILES) prefetch(tile);

    f32x4 h[8];
#pragma unroll
    for (int t = 0; t < 8; ++t) {
      h[t] = *(const f32x4*)(b1 + 16*t + 4*g);
      h[t] = __builtin_amdgcn_mfma_f32_16x16x32_bf16(w1f[t], xf, h[t], 0, 0, 0);
    }

    f32x4 o[4];
#pragma unroll
    for (int mt = 0; mt < 4; ++mt)
      o[mt] = *(const f32x4*)(b2 + 16*mt + 4*g);
#pragma unroll
    for (int ks = 0; ks < 4; ++ks) {
      bf16x8 bp;
#pragma unroll
      for (int j = 0; j < 8; ++j) {
        float v = h[2*ks + (j>>2)][j & 3];
        v = fmaxf(v, 0.0f);
        bp[j] = (__bf16)v;
      }
#pragma unroll
      for (int mt = 0; mt < 4; ++mt) {
        bf16x8 w2f = *(const bf16x8*)(w2p + (size_t)((mt*4 + ks)*64 + l)*8);
        o[mt] = __builtin_amdgcn_mfma_f32_16x16x32_bf16(w2f, bp, o[mt], 0, 0, 0);
      }
    }

    float* op = out + (size_t)(cur*16 + c)*64 + 4*g;
#pragma unroll
    for (int mt = 0; mt < 4; ++mt)
      *(f32x4*)(op + 16*mt) = o[mt];

    if (tile >= NTILES) break;
  }
}

extern "C" void kernel_launch(void* const* d_in, const int* in_sizes, int n_in,
                              void* d_out, int out_size, void* d_ws, size_t ws_size,
                              hipStream_t stream) {
  const float* coords = (const float*)d_in[0];
  const float* tables = (const float*)d_in[1];
  const float* W1     = (const float*)d_in[2];
  const float* b1     = (const float*)d_in[3];
  const float* W2     = (const float*)d_in[4];
  const float* b2     = (const float*)d_in[5];
  float* out = (float*)d_out;

  short* w1p = (short*)d_ws;                       // 8 KB
  short* w2p = w1p + 4096;                         // 16 KB (ends at 24 KB)

  const size_t TB2_OFF = 32*1024;
  const size_t TB2_SZ  = (size_t)16 * 524288 * 4;  // 32 MB
  const size_t need = TB2_OFF + TB2_SZ;

  if (ws_size >= need) {
    unsigned* tb2 = (unsigned*)((char*)d_ws + TB2_OFF);
    tconv_prep_kernel<<<8198, 256, 0, stream>>>(tables, W1, W2, tb2, w1p, w2p);
    fused_kernel<<<4096, 256, 0, stream>>>(coords, tb2, b1, b2, w1p, w2p, out);
  } else {
    prep_kernel<<<6, 256, 0, stream>>>(W1, W2, w1p, w2p);
    const int blocks = 2048;
    hashgrid_mlp_kernel<<<blocks, 256, 0, stream>>>(coords, tables, b1, b2,
                                                    w1p, w2p, out, blocks*4);
  }
}

// Round 8
// 188.291 us; speedup vs baseline: 1.5274x; 1.5274x over previous
//
#include <hip/hip_runtime.h>
#include <stdint.h>

// Three-stage HashGrid encoder + 32->128(relu)->64 MLP, bf16 MFMA (16x16x32).
//
// R7 lesson (falsified alternative): fusing gather+MLP put all 16 levels
// live at once -> 32 MB table set thrashed the 4 MB/XCD L2 (FETCH 675 MB,
// 288 us). Level-phased gather through an xw round trip is ~3x better.
//
// Stage 0 (tconv_prep_kernel): tables fp32x2 -> packed bf16x2 (64->32 MB;
// bit-identical to casting gathered features later) + W1^T/W2^T fragment
// packing (shared k-map kappa(g,j)=16*(j>>2)+4g+(j&3) so layer-1's C
// fragment feeds layer-2's B fragment in-register).
//
// Stage 1 (gather_kernel): hard levels 5..15 (2 MB bf16 tables) in R5's
// balanced XCD-phased runs (1408 chunks/XCD, active table L2-resident).
// R8: easy levels 0..4 (tables total ~0.6 MB, L2-resident on EVERY XCD,
// no phasing needed) are gathered by ONE block per chunk for all 5 levels
// -> coords read once instead of 5x; easy blocks 5120 -> 1024.
//
// Stage 2 (mlp_kernel): R8: 8192 blocks x 2 tiles/wave (was 4096 x 4) for
// more TLP; all xw loads issued up-front; obuf LDS transpose so each out
// store covers a contiguous 1 KB (plain stores; nt regressed in R3).

typedef __attribute__((ext_vector_type(8))) __bf16 bf16x8;
typedef __attribute__((ext_vector_type(4))) float  f32x4;
typedef __attribute__((ext_vector_type(2))) float  f32x2;

#define NPTS   1048576
#define NTILES 65536

__device__ __forceinline__ unsigned pack_bf16(float x, float y) {
  __bf16 a = (__bf16)x, b = (__bf16)y;
  unsigned short ua, ub;
  __builtin_memcpy(&ua, &a, 2);
  __builtin_memcpy(&ub, &b, 2);
  return (unsigned)ua | ((unsigned)ub << 16);
}

// ---------------- Stage 0: table bf16 conversion + weight prep ----------
__global__ __launch_bounds__(256) void tconv_prep_kernel(
    const float* __restrict__ tables,
    const float* __restrict__ W1, const float* __restrict__ W2,
    unsigned* __restrict__ tb2, short* __restrict__ w1p, short* __restrict__ w2p)
{
  if (blockIdx.x < 8192) {
    int e0 = (blockIdx.x * 256 + threadIdx.x) * 4;
#pragma unroll
    for (int i = 0; i < 4; ++i) {
      int e = e0 + i;
      f32x2 f = *(const f32x2*)(tables + (size_t)e * 2);
      tb2[e] = pack_bf16(f.x, f.y);
    }
    return;
  }
  int tid = (blockIdx.x - 8192) * 256 + threadIdx.x;   // 0..1535
  int l = tid & 63;
  int g = l >> 4;
  int c = l & 15;
  if (tid < 512) {
    int t = tid >> 6;
    bf16x8 v;
#pragma unroll
    for (int j = 0; j < 8; ++j)
      v[j] = (__bf16)W1[(8*g + j)*128 + 16*t + c];
    *(bf16x8*)(w1p + (size_t)(t*64 + l)*8) = v;
  } else if (tid < 1536) {
    int e = (tid - 512) >> 6;
    int mt = e >> 2, ks = e & 3;
    bf16x8 v;
#pragma unroll
    for (int j = 0; j < 8; ++j)
      v[j] = (__bf16)W2[(32*ks + 16*(j>>2) + 4*g + (j&3))*64 + 16*mt + c];
    *(bf16x8*)(w2p + (size_t)(e*64 + l)*8) = v;
  }
}

// ---------------- Stage 1: balanced XCD-phased level gather ----------------
// grid = 12288; bid = j*8 + xcd (round-robin dispatch -> bid&7 = XCD).
// j < 1408: hard chunk, contiguous per-XCD run over levels 5..15.
// j >= 1408: easy chunk (all levels 0..4 in one block, coords read once).
__global__ __launch_bounds__(256) void gather_kernel(
    const float* __restrict__ coords, const unsigned* __restrict__ tb2,
    unsigned* __restrict__ xw)
{
  constexpr unsigned Rt[16] = {16u,22u,30u,42u,58u,80u,111u,153u,
                               212u,294u,406u,561u,776u,1072u,1482u,2048u};
  const int xcd = blockIdx.x & 7;
  const int j   = blockIdx.x >> 3;

  if (j < 1408) {
    // ---- hard level (5..15), one level per block ----
    int ghi = xcd * 1408 + j;          // 0..11263
    int lv = 5 + (ghi >> 10);          // 5..15
    int chunk = ghi & 1023;

    const unsigned R = Rt[lv];
    const float fR = (float)R;
    const unsigned RR = R * R;
    const unsigned Rm1 = R - 1u;
    // lv>=6: T=2^19 (mask); lv==5: 80^3=512000 = T -> idx < T already.
    const unsigned M = (lv >= 6) ? 0x7FFFFu : 0xFFFFFFFFu;
    const unsigned* tb = tb2 + ((size_t)lv << 19);
    unsigned* xp = xw + ((size_t)lv << 20);

    int p0 = chunk * 1024 + threadIdx.x;
#pragma unroll
    for (int i = 0; i < 4; ++i) {      // 4 independent gather chains
      int p = p0 + (i << 8);
      float u0 = (coords[3*p+0] + 1.0f) * 0.5f;
      float u1 = (coords[3*p+1] + 1.0f) * 0.5f;
      float u2 = (coords[3*p+2] + 1.0f) * 0.5f;
      unsigned d0 = (unsigned)(int)(u0 * fR); if (d0 > Rm1) d0 = Rm1;
      unsigned d1 = (unsigned)(int)(u1 * fR); if (d1 > Rm1) d1 = Rm1;
      unsigned d2 = (unsigned)(int)(u2 * fR); if (d2 > Rm1) d2 = Rm1;
      // uint32 wraparound matches reference (T=2^19 divides 2^32 when masked)
      unsigned idx = (d0*RR + d1*R + d2) & M;
      xp[p] = tb[idx];                 // bf16x2, stored verbatim
    }
  } else {
    // ---- easy levels 0..4 combined: tables ~0.6 MB, L2-hit everywhere ----
    int chunk = xcd * 128 + (j - 1408);   // 0..1023
    int p0 = chunk * 1024 + threadIdx.x;
#pragma unroll
    for (int i = 0; i < 4; ++i) {
      int p = p0 + (i << 8);
      float u0 = (coords[3*p+0] + 1.0f) * 0.5f;
      float u1 = (coords[3*p+1] + 1.0f) * 0.5f;
      float u2 = (coords[3*p+2] + 1.0f) * 0.5f;
#pragma unroll
      for (int lv = 0; lv < 5; ++lv) {
        const unsigned R = Rt[lv];
        const unsigned Rm1 = R - 1u;
        unsigned d0 = (unsigned)(int)(u0 * (float)R); if (d0 > Rm1) d0 = Rm1;
        unsigned d1 = (unsigned)(int)(u1 * (float)R); if (d1 > Rm1) d1 = Rm1;
        unsigned d2 = (unsigned)(int)(u2 * (float)R); if (d2 > Rm1) d2 = Rm1;
        unsigned idx = d0*(R*R) + d1*R + d2;   // < R^3 = T, no mod needed
        xw[((size_t)lv << 20) + p] = tb2[((size_t)lv << 19) + idx];
      }
    }
  }
}

// ---------------- Stage 2: streaming MFMA MLP ----------------
// 8192 blocks x 4 waves; wave owns tiles base + it*32768, it = 0..1 (exact).
__global__ __launch_bounds__(256, 4) void mlp_kernel(
    const unsigned* __restrict__ xw,
    const float* __restrict__ b1, const float* __restrict__ b2,
    const short* __restrict__ w1p, const short* __restrict__ w2p,
    float* __restrict__ out)
{
  const int l = threadIdx.x & 63;
  const int g = l >> 4;
  const int c = l & 15;
  const int w = threadIdx.x >> 6;

  __shared__ float obuf[4][16][68];   // per-wave transpose buffer

  bf16x8 w1f[8];
#pragma unroll
  for (int t = 0; t < 8; ++t)
    w1f[t] = *(const bf16x8*)(w1p + (size_t)(t*64 + l)*8);

  const int base = blockIdx.x * 4 + w;

  unsigned gx[2][4];
#pragma unroll
  for (int it = 0; it < 2; ++it) {
    int p = (base + it*32768)*16 + c;
#pragma unroll
    for (int q = 0; q < 4; ++q)
      gx[it][q] = xw[((size_t)(4*g + q) << 20) + p];
  }

#pragma unroll
  for (int it = 0; it < 2; ++it) {
    union { bf16x8 v; unsigned u[4]; } X;
#pragma unroll
    for (int q = 0; q < 4; ++q) X.u[q] = gx[it][q];
    bf16x8 xf = X.v;

    f32x4 h[8];
#pragma unroll
    for (int t = 0; t < 8; ++t) {
      h[t] = *(const f32x4*)(b1 + 16*t + 4*g);
      h[t] = __builtin_amdgcn_mfma_f32_16x16x32_bf16(w1f[t], xf, h[t], 0, 0, 0);
    }

    f32x4 o[4];
#pragma unroll
    for (int mt = 0; mt < 4; ++mt)
      o[mt] = *(const f32x4*)(b2 + 16*mt + 4*g);
#pragma unroll
    for (int ks = 0; ks < 4; ++ks) {
      bf16x8 bp;
#pragma unroll
      for (int j = 0; j < 8; ++j) {
        float v = h[2*ks + (j>>2)][j & 3];
        v = fmaxf(v, 0.0f);               // fused ReLU
        bp[j] = (__bf16)v;
      }
#pragma unroll
      for (int mt = 0; mt < 4; ++mt) {
        bf16x8 w2f = *(const bf16x8*)(w2p + (size_t)((mt*4 + ks)*64 + l)*8);
        o[mt] = __builtin_amdgcn_mfma_f32_16x16x32_bf16(w2f, bp, o[mt], 0, 0, 0);
      }
    }

    // LDS transpose -> each store instruction covers contiguous 1 KB.
    float (*ob)[68] = obuf[w];
#pragma unroll
    for (int mt = 0; mt < 4; ++mt)
      *(f32x4*)&ob[c][16*mt + 4*g] = o[mt];
    asm volatile("s_waitcnt lgkmcnt(0)" ::: "memory");   // wave-local fence
    f32x4 v[4];
#pragma unroll
    for (int s = 0; s < 4; ++s)
      v[s] = *(const f32x4*)&ob[4*s + g][4*c];
    asm volatile("" ::: "memory");
    float* op = out + (size_t)(base + it*32768) * 1024;
#pragma unroll
    for (int s = 0; s < 4; ++s)
      *(f32x4*)(op + (4*s + g)*64 + 4*c) = v[s];   // plain stores

    if (it < 1) asm volatile("s_waitcnt lgkmcnt(0)" ::: "memory");
  }
}

// ---------------- R1 fused kernel kept as fallback (ws too small) ----------
__global__ void prep_kernel(const float* __restrict__ W1, const float* __restrict__ W2,
                            short* __restrict__ w1p, short* __restrict__ w2p) {
  int tid = blockIdx.x * blockDim.x + threadIdx.x;
  int l = tid & 63;
  int g = l >> 4;
  int c = l & 15;
  if (tid < 512) {
    int t = tid >> 6;
    bf16x8 v;
#pragma unroll
    for (int j = 0; j < 8; ++j)
      v[j] = (__bf16)W1[(8*g + j)*128 + 16*t + c];
    *(bf16x8*)(w1p + (size_t)(t*64 + l)*8) = v;
  } else if (tid < 1536) {
    int e = (tid - 512) >> 6;
    int mt = e >> 2, ks = e & 3;
    bf16x8 v;
#pragma unroll
    for (int j = 0; j < 8; ++j)
      v[j] = (__bf16)W2[(32*ks + 16*(j>>2) + 4*g + (j&3))*64 + 16*mt + c];
    *(bf16x8*)(w2p + (size_t)(e*64 + l)*8) = v;
  }
}

__device__ const unsigned kRES[16] = {16u,22u,30u,42u,58u,80u,111u,153u,
                                      212u,294u,406u,561u,776u,1072u,1482u,2048u};

__global__ __launch_bounds__(256, 3) void hashgrid_mlp_kernel(
    const float* __restrict__ coords, const float* __restrict__ tables,
    const float* __restrict__ b1, const float* __restrict__ b2,
    const short* __restrict__ w1p, const short* __restrict__ w2p,
    float* __restrict__ out, int stride)
{
  const int l = threadIdx.x & 63;
  const int g = l >> 4;
  const int c = l & 15;

  unsigned Rq[4], RRq[4], Mq[4]; float fRq[4];
#pragma unroll
  for (int q = 0; q < 4; ++q) {
    int lv = 4*g + q;
    unsigned R = kRES[lv];
    Rq[q] = R; RRq[q] = R*R; fRq[q] = (float)R;
    Mq[q] = (lv >= 6) ? 0x7FFFFu : 0xFFFFFFFFu;
  }
  const float* tb = tables + ((size_t)g << 22);

  bf16x8 w1f[8];
#pragma unroll
  for (int t = 0; t < 8; ++t)
    w1f[t] = *(const bf16x8*)(w1p + (size_t)(t*64 + l)*8);

  f32x2 gx[4];
  auto prefetch = [&](int tile) {
    int p = tile*16 + c;
    float u0 = (coords[3*p+0] + 1.0f) * 0.5f;
    float u1 = (coords[3*p+1] + 1.0f) * 0.5f;
    float u2 = (coords[3*p+2] + 1.0f) * 0.5f;
#pragma unroll
    for (int q = 0; q < 4; ++q) {
      unsigned Rm1 = Rq[q] - 1u;
      unsigned d0 = (unsigned)(int)(u0 * fRq[q]); if (d0 > Rm1) d0 = Rm1;
      unsigned d1 = (unsigned)(int)(u1 * fRq[q]); if (d1 > Rm1) d1 = Rm1;
      unsigned d2 = (unsigned)(int)(u2 * fRq[q]); if (d2 > Rm1) d2 = Rm1;
      unsigned idx = (d0*RRq[q] + d1*Rq[q] + d2) & Mq[q];
      gx[q] = *(const f32x2*)(tb + ((size_t)q << 20) + (size_t)idx*2u);
    }
  };

  int tile = blockIdx.x * 4 + (threadIdx.x >> 6);
  prefetch(tile);
  while (true) {
    bf16x8 xf;
#pragma unroll
    for (int q = 0; q < 4; ++q) {
      xf[2*q]   = (__bf16)gx[q].x;
      xf[2*q+1] = (__bf16)gx[q].y;
    }
    int cur = tile;
    tile += stride;
    if (tile < NTILES) prefetch(tile);

    f32x4 h[8];
#pragma unroll
    for (int t = 0; t < 8; ++t) {
      h[t] = *(const f32x4*)(b1 + 16*t + 4*g);
      h[t] = __builtin_amdgcn_mfma_f32_16x16x32_bf16(w1f[t], xf, h[t], 0, 0, 0);
    }

    f32x4 o[4];
#pragma unroll
    for (int mt = 0; mt < 4; ++mt)
      o[mt] = *(const f32x4*)(b2 + 16*mt + 4*g);
#pragma unroll
    for (int ks = 0; ks < 4; ++ks) {
      bf16x8 bp;
#pragma unroll
      for (int j = 0; j < 8; ++j) {
        float v = h[2*ks + (j>>2)][j & 3];
        v = fmaxf(v, 0.0f);
        bp[j] = (__bf16)v;
      }
#pragma unroll
      for (int mt = 0; mt < 4; ++mt) {
        bf16x8 w2f = *(const bf16x8*)(w2p + (size_t)((mt*4 + ks)*64 + l)*8);
        o[mt] = __builtin_amdgcn_mfma_f32_16x16x32_bf16(w2f, bp, o[mt], 0, 0, 0);
      }
    }

    float* op = out + (size_t)(cur*16 + c)*64 + 4*g;
#pragma unroll
    for (int mt = 0; mt < 4; ++mt)
      *(f32x4*)(op + 16*mt) = o[mt];

    if (tile >= NTILES) break;
  }
}

extern "C" void kernel_launch(void* const* d_in, const int* in_sizes, int n_in,
                              void* d_out, int out_size, void* d_ws, size_t ws_size,
                              hipStream_t stream) {
  const float* coords = (const float*)d_in[0];
  const float* tables = (const float*)d_in[1];
  const float* W1     = (const float*)d_in[2];
  const float* b1     = (const float*)d_in[3];
  const float* W2     = (const float*)d_in[4];
  const float* b2     = (const float*)d_in[5];
  float* out = (float*)d_out;

  short* w1p = (short*)d_ws;                       // 8 KB
  short* w2p = w1p + 4096;                         // 16 KB (ends at 24 KB)

  const size_t XW_OFF  = 32*1024;
  const size_t XW_SZ   = (size_t)NPTS * 16 * 4;    // 64 MB
  const size_t TB2_SZ  = (size_t)16 * 524288 * 4;  // 32 MB
  const size_t need = XW_OFF + XW_SZ + TB2_SZ;

  if (ws_size >= need) {
    unsigned* xw  = (unsigned*)((char*)d_ws + XW_OFF);
    unsigned* tb2 = (unsigned*)((char*)d_ws + XW_OFF + XW_SZ);
    tconv_prep_kernel<<<8198, 256, 0, stream>>>(tables, W1, W2, tb2, w1p, w2p);
    gather_kernel<<<12288, 256, 0, stream>>>(coords, tb2, xw);
    mlp_kernel<<<8192, 256, 0, stream>>>(xw, b1, b2, w1p, w2p, out);
  } else {
    prep_kernel<<<6, 256, 0, stream>>>(W1, W2, w1p, w2p);
    const int blocks = 2048;
    hashgrid_mlp_kernel<<<blocks, 256, 0, stream>>>(coords, tables, b1, b2,
                                                    w1p, w2p, out, blocks*4);
  }
}

// Round 9
// 187.130 us; speedup vs baseline: 1.5369x; 1.0062x over previous
//
#include <hip/hip_runtime.h>
#include <stdint.h>

// Three-stage HashGrid encoder + 32->128(relu)->64 MLP, bf16 MFMA (16x16x32).
//
// R7 lesson: full fusion thrashes L2 (16 live tables, FETCH 675 MB). Level-
// phased gather through an xw round trip is ~3x better. R8 lesson: easy-
// combined gather and mlp TLP were neutral -> passes limited by L2 random-
// sector traffic (gather) and output-write BW (mlp).
//
// Stage 0 (tconv_prep_kernel): R9 —
//   blocks [0,1024):    EASY GATHER levels 0..4 directly from fp32 tables
//                       (2.5 MB total, L2-resident everywhere; bf16 cast of
//                       fp32 lookup is bit-identical to tb2 lookup). These
//                       latency-bound gathers overlap the streaming blocks.
//   blocks [1024,6656): convert ONLY hard levels 5..15 fp32x2 -> bf16x2
//                       (44 MB read / 22 MB write, was 64/32).
//   blocks [6656,6662): W1^T/W2^T fragment packing (shared k-map
//                       kappa(g,j)=16*(j>>2)+4g+(j&3) so layer-1's C
//                       fragment feeds layer-2's B fragment in-register).
//
// Stage 1 (gather_kernel): pure hard levels 5..15, R5's balanced XCD-phased
// schedule (1408 chunks per XCD, active 2 MB bf16 table L2-resident).
//
// Stage 2 (mlp_kernel): 8192 blocks x 2 tiles/wave; all xw loads up-front;
// obuf LDS transpose so each out store covers a contiguous 1 KB (plain
// stores; nontemporal regressed in R3).

typedef __attribute__((ext_vector_type(8))) __bf16 bf16x8;
typedef __attribute__((ext_vector_type(4))) float  f32x4;
typedef __attribute__((ext_vector_type(2))) float  f32x2;

#define NPTS   1048576
#define NTILES 65536

__device__ __forceinline__ unsigned pack_bf16(float x, float y) {
  __bf16 a = (__bf16)x, b = (__bf16)y;
  unsigned short ua, ub;
  __builtin_memcpy(&ua, &a, 2);
  __builtin_memcpy(&ub, &b, 2);
  return (unsigned)ua | ((unsigned)ub << 16);
}

// ---------------- Stage 0: easy gather + hard table conv + weight prep ----
__global__ __launch_bounds__(256) void tconv_prep_kernel(
    const float* __restrict__ coords, const float* __restrict__ tables,
    const float* __restrict__ W1, const float* __restrict__ W2,
    unsigned* __restrict__ tb2, unsigned* __restrict__ xw,
    short* __restrict__ w1p, short* __restrict__ w2p)
{
  constexpr unsigned Rt[5] = {16u,22u,30u,42u,58u};
  if (blockIdx.x < 1024) {
    // ---- easy levels 0..4: gather from fp32 tables (L2-resident) ----
    int p0 = blockIdx.x * 1024 + threadIdx.x;
#pragma unroll
    for (int i = 0; i < 4; ++i) {
      int p = p0 + (i << 8);
      float u0 = (coords[3*p+0] + 1.0f) * 0.5f;
      float u1 = (coords[3*p+1] + 1.0f) * 0.5f;
      float u2 = (coords[3*p+2] + 1.0f) * 0.5f;
#pragma unroll
      for (int lv = 0; lv < 5; ++lv) {
        const unsigned R = Rt[lv];
        const unsigned Rm1 = R - 1u;
        unsigned d0 = (unsigned)(int)(u0 * (float)R); if (d0 > Rm1) d0 = Rm1;
        unsigned d1 = (unsigned)(int)(u1 * (float)R); if (d1 > Rm1) d1 = Rm1;
        unsigned d2 = (unsigned)(int)(u2 * (float)R); if (d2 > Rm1) d2 = Rm1;
        unsigned idx = d0*(R*R) + d1*R + d2;   // < R^3 = T, no mod needed
        f32x2 f = *(const f32x2*)(tables + ((size_t)lv << 20) + (size_t)idx*2u);
        xw[((size_t)lv << 20) + p] = pack_bf16(f.x, f.y);  // bit-identical
      }
    }
    return;
  }
  if (blockIdx.x < 6656) {
    // ---- convert hard levels 5..15 (11 x 2^19 entries) ----
    int e0 = 5*524288 + ((int)(blockIdx.x - 1024) * 256 + (int)threadIdx.x) * 4;
#pragma unroll
    for (int i = 0; i < 4; ++i) {
      int e = e0 + i;
      f32x2 f = *(const f32x2*)(tables + (size_t)e * 2);
      tb2[e] = pack_bf16(f.x, f.y);
    }
    return;
  }
  // ---- weight fragment packing ----
  int tid = (blockIdx.x - 6656) * 256 + threadIdx.x;   // 0..1535
  int l = tid & 63;
  int g = l >> 4;
  int c = l & 15;
  if (tid < 512) {
    int t = tid >> 6;
    bf16x8 v;
#pragma unroll
    for (int j = 0; j < 8; ++j)
      v[j] = (__bf16)W1[(8*g + j)*128 + 16*t + c];
    *(bf16x8*)(w1p + (size_t)(t*64 + l)*8) = v;
  } else if (tid < 1536) {
    int e = (tid - 512) >> 6;
    int mt = e >> 2, ks = e & 3;
    bf16x8 v;
#pragma unroll
    for (int j = 0; j < 8; ++j)
      v[j] = (__bf16)W2[(32*ks + 16*(j>>2) + 4*g + (j&3))*64 + 16*mt + c];
    *(bf16x8*)(w2p + (size_t)(e*64 + l)*8) = v;
  }
}

// ---------------- Stage 1: balanced XCD-phased hard-level gather ----------
// grid = 11264; bid = j*8 + xcd (round-robin dispatch -> bid&7 = XCD).
// Per XCD: contiguous run of 1408 chunks over levels 5..15.
__global__ __launch_bounds__(256) void gather_kernel(
    const float* __restrict__ coords, const unsigned* __restrict__ tb2,
    unsigned* __restrict__ xw)
{
  constexpr unsigned Rt[16] = {16u,22u,30u,42u,58u,80u,111u,153u,
                               212u,294u,406u,561u,776u,1072u,1482u,2048u};
  const int xcd = blockIdx.x & 7;
  const int j   = blockIdx.x >> 3;          // 0..1407
  int ghi = xcd * 1408 + j;                 // 0..11263
  int lv = 5 + (ghi >> 10);                 // 5..15
  int chunk = ghi & 1023;

  const unsigned R = Rt[lv];
  const float fR = (float)R;
  const unsigned RR = R * R;
  const unsigned Rm1 = R - 1u;
  // lv>=6: T=2^19 (mask); lv==5: 80^3=512000 = T -> idx < T already.
  const unsigned M = (lv >= 6) ? 0x7FFFFu : 0xFFFFFFFFu;
  const unsigned* tb = tb2 + ((size_t)lv << 19);
  unsigned* xp = xw + ((size_t)lv << 20);

  int p0 = chunk * 1024 + threadIdx.x;
#pragma unroll
  for (int i = 0; i < 4; ++i) {             // 4 independent gather chains
    int p = p0 + (i << 8);
    float u0 = (coords[3*p+0] + 1.0f) * 0.5f;
    float u1 = (coords[3*p+1] + 1.0f) * 0.5f;
    float u2 = (coords[3*p+2] + 1.0f) * 0.5f;
    unsigned d0 = (unsigned)(int)(u0 * fR); if (d0 > Rm1) d0 = Rm1;
    unsigned d1 = (unsigned)(int)(u1 * fR); if (d1 > Rm1) d1 = Rm1;
    unsigned d2 = (unsigned)(int)(u2 * fR); if (d2 > Rm1) d2 = Rm1;
    // uint32 wraparound matches reference (T=2^19 divides 2^32 when masked)
    unsigned idx = (d0*RR + d1*R + d2) & M;
    xp[p] = tb[idx];                        // bf16x2, stored verbatim
  }
}

// ---------------- Stage 2: streaming MFMA MLP ----------------
// 8192 blocks x 4 waves; wave owns tiles base + it*32768, it = 0..1 (exact).
__global__ __launch_bounds__(256, 4) void mlp_kernel(
    const unsigned* __restrict__ xw,
    const float* __restrict__ b1, const float* __restrict__ b2,
    const short* __restrict__ w1p, const short* __restrict__ w2p,
    float* __restrict__ out)
{
  const int l = threadIdx.x & 63;
  const int g = l >> 4;
  const int c = l & 15;
  const int w = threadIdx.x >> 6;

  __shared__ float obuf[4][16][68];   // per-wave transpose buffer

  bf16x8 w1f[8];
#pragma unroll
  for (int t = 0; t < 8; ++t)
    w1f[t] = *(const bf16x8*)(w1p + (size_t)(t*64 + l)*8);

  const int base = blockIdx.x * 4 + w;

  unsigned gx[2][4];
#pragma unroll
  for (int it = 0; it < 2; ++it) {
    int p = (base + it*32768)*16 + c;
#pragma unroll
    for (int q = 0; q < 4; ++q)
      gx[it][q] = xw[((size_t)(4*g + q) << 20) + p];
  }

#pragma unroll
  for (int it = 0; it < 2; ++it) {
    union { bf16x8 v; unsigned u[4]; } X;
#pragma unroll
    for (int q = 0; q < 4; ++q) X.u[q] = gx[it][q];
    bf16x8 xf = X.v;

    f32x4 h[8];
#pragma unroll
    for (int t = 0; t < 8; ++t) {
      h[t] = *(const f32x4*)(b1 + 16*t + 4*g);
      h[t] = __builtin_amdgcn_mfma_f32_16x16x32_bf16(w1f[t], xf, h[t], 0, 0, 0);
    }

    f32x4 o[4];
#pragma unroll
    for (int mt = 0; mt < 4; ++mt)
      o[mt] = *(const f32x4*)(b2 + 16*mt + 4*g);
#pragma unroll
    for (int ks = 0; ks < 4; ++ks) {
      bf16x8 bp;
#pragma unroll
      for (int j = 0; j < 8; ++j) {
        float v = h[2*ks + (j>>2)][j & 3];
        v = fmaxf(v, 0.0f);               // fused ReLU
        bp[j] = (__bf16)v;
      }
#pragma unroll
      for (int mt = 0; mt < 4; ++mt) {
        bf16x8 w2f = *(const bf16x8*)(w2p + (size_t)((mt*4 + ks)*64 + l)*8);
        o[mt] = __builtin_amdgcn_mfma_f32_16x16x32_bf16(w2f, bp, o[mt], 0, 0, 0);
      }
    }

    // LDS transpose -> each store instruction covers contiguous 1 KB.
    float (*ob)[68] = obuf[w];
#pragma unroll
    for (int mt = 0; mt < 4; ++mt)
      *(f32x4*)&ob[c][16*mt + 4*g] = o[mt];
    asm volatile("s_waitcnt lgkmcnt(0)" ::: "memory");   // wave-local fence
    f32x4 v[4];
#pragma unroll
    for (int s = 0; s < 4; ++s)
      v[s] = *(const f32x4*)&ob[4*s + g][4*c];
    asm volatile("" ::: "memory");
    float* op = out + (size_t)(base + it*32768) * 1024;
#pragma unroll
    for (int s = 0; s < 4; ++s)
      *(f32x4*)(op + (4*s + g)*64 + 4*c) = v[s];   // plain stores

    if (it < 1) asm volatile("s_waitcnt lgkmcnt(0)" ::: "memory");
  }
}

// ---------------- R1 fused kernel kept as fallback (ws too small) ----------
__global__ void prep_kernel(const float* __restrict__ W1, const float* __restrict__ W2,
                            short* __restrict__ w1p, short* __restrict__ w2p) {
  int tid = blockIdx.x * blockDim.x + threadIdx.x;
  int l = tid & 63;
  int g = l >> 4;
  int c = l & 15;
  if (tid < 512) {
    int t = tid >> 6;
    bf16x8 v;
#pragma unroll
    for (int j = 0; j < 8; ++j)
      v[j] = (__bf16)W1[(8*g + j)*128 + 16*t + c];
    *(bf16x8*)(w1p + (size_t)(t*64 + l)*8) = v;
  } else if (tid < 1536) {
    int e = (tid - 512) >> 6;
    int mt = e >> 2, ks = e & 3;
    bf16x8 v;
#pragma unroll
    for (int j = 0; j < 8; ++j)
      v[j] = (__bf16)W2[(32*ks + 16*(j>>2) + 4*g + (j&3))*64 + 16*mt + c];
    *(bf16x8*)(w2p + (size_t)(e*64 + l)*8) = v;
  }
}

__device__ const unsigned kRES[16] = {16u,22u,30u,42u,58u,80u,111u,153u,
                                      212u,294u,406u,561u,776u,1072u,1482u,2048u};

__global__ __launch_bounds__(256, 3) void hashgrid_mlp_kernel(
    const float* __restrict__ coords, const float* __restrict__ tables,
    const float* __restrict__ b1, const float* __restrict__ b2,
    const short* __restrict__ w1p, const short* __restrict__ w2p,
    float* __restrict__ out, int stride)
{
  const int l = threadIdx.x & 63;
  const int g = l >> 4;
  const int c = l & 15;

  unsigned Rq[4], RRq[4], Mq[4]; float fRq[4];
#pragma unroll
  for (int q = 0; q < 4; ++q) {
    int lv = 4*g + q;
    unsigned R = kRES[lv];
    Rq[q] = R; RRq[q] = R*R; fRq[q] = (float)R;
    Mq[q] = (lv >= 6) ? 0x7FFFFu : 0xFFFFFFFFu;
  }
  const float* tb = tables + ((size_t)g << 22);

  bf16x8 w1f[8];
#pragma unroll
  for (int t = 0; t < 8; ++t)
    w1f[t] = *(const bf16x8*)(w1p + (size_t)(t*64 + l)*8);

  f32x2 gx[4];
  auto prefetch = [&](int tile) {
    int p = tile*16 + c;
    float u0 = (coords[3*p+0] + 1.0f) * 0.5f;
    float u1 = (coords[3*p+1] + 1.0f) * 0.5f;
    float u2 = (coords[3*p+2] + 1.0f) * 0.5f;
#pragma unroll
    for (int q = 0; q < 4; ++q) {
      unsigned Rm1 = Rq[q] - 1u;
      unsigned d0 = (unsigned)(int)(u0 * fRq[q]); if (d0 > Rm1) d0 = Rm1;
      unsigned d1 = (unsigned)(int)(u1 * fRq[q]); if (d1 > Rm1) d1 = Rm1;
      unsigned d2 = (unsigned)(int)(u2 * fRq[q]); if (d2 > Rm1) d2 = Rm1;
      unsigned idx = (d0*RRq[q] + d1*Rq[q] + d2) & Mq[q];
      gx[q] = *(const f32x2*)(tb + ((size_t)q << 20) + (size_t)idx*2u);
    }
  };

  int tile = blockIdx.x * 4 + (threadIdx.x >> 6);
  prefetch(tile);
  while (true) {
    bf16x8 xf;
#pragma unroll
    for (int q = 0; q < 4; ++q) {
      xf[2*q]   = (__bf16)gx[q].x;
      xf[2*q+1] = (__bf16)gx[q].y;
    }
    int cur = tile;
    tile += stride;
    if (tile < NTILES) prefetch(tile);

    f32x4 h[8];
#pragma unroll
    for (int t = 0; t < 8; ++t) {
      h[t] = *(const f32x4*)(b1 + 16*t + 4*g);
      h[t] = __builtin_amdgcn_mfma_f32_16x16x32_bf16(w1f[t], xf, h[t], 0, 0, 0);
    }

    f32x4 o[4];
#pragma unroll
    for (int mt = 0; mt < 4; ++mt)
      o[mt] = *(const f32x4*)(b2 + 16*mt + 4*g);
#pragma unroll
    for (int ks = 0; ks < 4; ++ks) {
      bf16x8 bp;
#pragma unroll
      for (int j = 0; j < 8; ++j) {
        float v = h[2*ks + (j>>2)][j & 3];
        v = fmaxf(v, 0.0f);
        bp[j] = (__bf16)v;
      }
#pragma unroll
      for (int mt = 0; mt < 4; ++mt) {
        bf16x8 w2f = *(const bf16x8*)(w2p + (size_t)((mt*4 + ks)*64 + l)*8);
        o[mt] = __builtin_amdgcn_mfma_f32_16x16x32_bf16(w2f, bp, o[mt], 0, 0, 0);
      }
    }

    float* op = out + (size_t)(cur*16 + c)*64 + 4*g;
#pragma unroll
    for (int mt = 0; mt < 4; ++mt)
      *(f32x4*)(op + 16*mt) = o[mt];

    if (tile >= NTILES) break;
  }
}

extern "C" void kernel_launch(void* const* d_in, const int* in_sizes, int n_in,
                              void* d_out, int out_size, void* d_ws, size_t ws_size,
                              hipStream_t stream) {
  const float* coords = (const float*)d_in[0];
  const float* tables = (const float*)d_in[1];
  const float* W1     = (const float*)d_in[2];
  const float* b1     = (const float*)d_in[3];
  const float* W2     = (const float*)d_in[4];
  const float* b2     = (const float*)d_in[5];
  float* out = (float*)d_out;

  short* w1p = (short*)d_ws;                       // 8 KB
  short* w2p = w1p + 4096;                         // 16 KB (ends at 24 KB)

  const size_t XW_OFF  = 32*1024;
  const size_t XW_SZ   = (size_t)NPTS * 16 * 4;    // 64 MB
  const size_t TB2_SZ  = (size_t)16 * 524288 * 4;  // 32 MB
  const size_t need = XW_OFF + XW_SZ + TB2_SZ;

  if (ws_size >= need) {
    unsigned* xw  = (unsigned*)((char*)d_ws + XW_OFF);
    unsigned* tb2 = (unsigned*)((char*)d_ws + XW_OFF + XW_SZ);
    tconv_prep_kernel<<<6662, 256, 0, stream>>>(coords, tables, W1, W2,
                                                tb2, xw, w1p, w2p);
    gather_kernel<<<11264, 256, 0, stream>>>(coords, tb2, xw);
    mlp_kernel<<<8192, 256, 0, stream>>>(xw, b1, b2, w1p, w2p, out);
  } else {
    prep_kernel<<<6, 256, 0, stream>>>(W1, W2, w1p, w2p);
    const int blocks = 2048;
    hashgrid_mlp_kernel<<<blocks, 256, 0, stream>>>(coords, tables, b1, b2,
                                                    w1p, w2p, out, blocks*4);
  }
}